// Round 4
// baseline (3357.855 us; speedup 1.0000x reference)
//
#include <hip/hip_runtime.h>

// DSTP-RNN fused forward v2: one batch element per 512-thread WG (8 waves).
// 512 WGs -> 2 WG/CU -> 16 waves/CU = 4 waves/SIMD (2x round-2 occupancy).
// Uenc computed once post-encoder (transposed [64][136] for conflict-free reads).
// LDS 80496 B/WG -> 2 WG/CU (160992 of 163840).

#define TSTEPS 128

// LDS float offsets
#define ENC    0        // [128][64] encoded h
#define UENC   8192     // [64][136] Uenc transposed, stride 136 (8 mod 32 -> 2-way reads)
#define UE     16896    // [128][8] Ue_w f32 (encoder) ; decoder const pool overlays
#define CTL    17920    // [64][8] conv tile (encoder) ; yh row overlays (decoder)
#define XVE    18432    // [128][2] interleaved (x_j, ve_j) / (x1_j, vd_j)
#define HSB    18688    // [128] h|s (enc), d|sp (dec)
#define GBUF   18816    // [512] partials (enc preact 256 / dec c_t partials 512)
#define RED    19328    // [512] enc e-partials ; GB2 (dec preacts 256) overlays
#define REDS   19840    // [8] scalars
#define IMG    19848    // [84] 9x9 image ; TYP (head, 64) overlays
#define CTV    19932    // [64] decoder c_t
#define LBUF   19996    // [128] l / beta
#define SMEMF  20124    // floats -> 80496 bytes

// decoder const overlays (UE region, loaded after encoder)
#define DC_VD    16896
#define DC_WT    16960   // 65
#define DC_DWIH  17152   // 256
#define DC_DBIAS 17408   // 256
#define DC_WDB   17664   // 64
#define DC_WYB   17728   // 64
#define DC_VY    17792   // 64
#define DC_SC    17856   // wtb, vyb
#define DC_YH    17920   // 128 (overlays CTL)
#define GB2      19328   // overlays RED
#define TYP      19848   // overlays IMG

__device__ __forceinline__ float rcpf(float x) { return __builtin_amdgcn_rcpf(x); }
__device__ __forceinline__ float fsigm(float x) { return rcpf(1.0f + __expf(-x)); }
__device__ __forceinline__ float ftanh(float x) { return 1.0f - 2.0f * rcpf(1.0f + __expf(2.0f * x)); }

// NOTE: parameter names must NOT collide with float4 member names (.x/.y/.z/.w)
// or the preprocessor rewrites the member accesses.
#define FMA4(d_, p_, q_) \
    d_ = fmaf((p_).x, (q_).x, d_); d_ = fmaf((p_).y, (q_).y, d_); \
    d_ = fmaf((p_).z, (q_).z, d_); d_ = fmaf((p_).w, (q_).w, d_);

__global__ __launch_bounds__(512, 4) void dstp_kernel(
    const float* __restrict__ Xh,   const float* __restrict__ yh,
    const float* __restrict__ convw,const float* __restrict__ convb,
    const float* __restrict__ Wew,  const float* __restrict__ Web,
    const float* __restrict__ Uew,  const float* __restrict__ vew,
    const float* __restrict__ eWih, const float* __restrict__ eWhh,
    const float* __restrict__ ebih, const float* __restrict__ ebhh,
    const float* __restrict__ Wdw,  const float* __restrict__ Wdb,
    const float* __restrict__ Udw,  const float* __restrict__ vdw,
    const float* __restrict__ wtw,  const float* __restrict__ wtb,
    const float* __restrict__ dWih, const float* __restrict__ dWhh,
    const float* __restrict__ dbih, const float* __restrict__ dbhh,
    const float* __restrict__ Wyw,  const float* __restrict__ Wyb,
    const float* __restrict__ vyw,  const float* __restrict__ vyb,
    float* __restrict__ out)
{
    extern __shared__ float sm[];
    const int tid = threadIdx.x;
    const int b   = blockIdx.x;

    // init: stage Ue_w f32, ve into XVE.y, zero h/s
    for (int i = tid; i < 1024; i += 512) sm[UE + i] = Uew[i];
    if (tid < 128) { sm[XVE + tid * 2 + 1] = vew[tid]; sm[HSB + tid] = 0.0f; }
    __syncthreads();

    // ===================== ENCODER =====================
    for (int t = 0; t < TSTEPS; ++t) {
        // img load + (c) x[j] = [h,s].We_w[j,:] + We_b[j]
        if (tid < 81) sm[IMG + tid] = Xh[((size_t)b * TSTEPS + t) * 81 + tid];
        {
            int j = tid >> 2, q = tid & 3;
            const float4* wr = reinterpret_cast<const float4*>(Wew + j * 128 + q * 32);
            const float4* hv = reinterpret_cast<const float4*>(sm + HSB + q * 32);
            float acc = 0.0f;
#pragma unroll
            for (int k = 0; k < 8; ++k) { float4 wv = wr[k], xv = hv[k]; FMA4(acc, wv, xv) }
            acc += __shfl_xor(acc, 1);
            acc += __shfl_xor(acc, 2);
            if (q == 0) sm[XVE + j * 2] = acc + Web[j];
        }
        __syncthreads(); // A
        // conv + relu
        {
            int m = tid >> 3, r = tid & 7;
            const float* kw = convw + m * 18;
            float acc = convb[m];
#pragma unroll
            for (int w = 0; w < 9; ++w) {
                acc = fmaf(sm[IMG + r * 9 + w],     kw[w],     acc);
                acc = fmaf(sm[IMG + r * 9 + 9 + w], kw[9 + w], acc);
            }
            sm[CTL + m * 8 + r] = fmaxf(acc, 0.0f);
        }
        __syncthreads(); // B
        const int m = tid & 63;
        const float4 c0 = *reinterpret_cast<const float4*>(sm + CTL + m * 8);
        const float4 c1 = *reinterpret_cast<const float4*>(sm + CTL + m * 8 + 4);
        // (d) e partials: lane=m, wave w covers 16 j (Ue rows broadcast)
        {
            int w = tid >> 6;
            float eacc = 0.0f;
#pragma unroll
            for (int jj = 0; jj < 16; ++jj) {
                int j = w * 16 + jj;
                float4 u0 = *reinterpret_cast<const float4*>(sm + UE + j * 8);
                float4 u1 = *reinterpret_cast<const float4*>(sm + UE + j * 8 + 4);
                float2 xv = *reinterpret_cast<const float2*>(sm + XVE + j * 2);
                float s = xv.x;
                FMA4(s, u0, c0) FMA4(s, u1, c1)
                eacc = fmaf(ftanh(s), xv.y, eacc);
            }
            sm[RED + (tid >> 6) * 64 + m] = eacc;
        }
        __syncthreads(); // C
        // (ef) per-wave redundant: e combine + softmax + w_in butterfly (all lanes end with w_in)
        float win[8];
        {
            float e = 0.0f;
#pragma unroll
            for (int p = 0; p < 8; ++p) e += sm[RED + p * 64 + m];
            float mx = e;
#pragma unroll
            for (int dd = 1; dd < 64; dd <<= 1) mx = fmaxf(mx, __shfl_xor(mx, dd));
            float ex = __expf(e - mx);
            float ssum = ex;
#pragma unroll
            for (int dd = 1; dd < 64; dd <<= 1) ssum += __shfl_xor(ssum, dd);
            float al = ex * rcpf(ssum);
            win[0] = al * c0.x; win[1] = al * c0.y; win[2] = al * c0.z; win[3] = al * c0.w;
            win[4] = al * c1.x; win[5] = al * c1.y; win[6] = al * c1.z; win[7] = al * c1.w;
#pragma unroll
            for (int dd = 1; dd < 64; dd <<= 1) {
#pragma unroll
                for (int c = 0; c < 8; ++c) win[c] += __shfl_xor(win[c], dd);
            }
        }
        // (g) LSTM preact row j (fused; w_in already in regs)
        {
            int j = tid >> 1, hk = tid & 1;
            const float4* whh = reinterpret_cast<const float4*>(eWhh + j * 64 + hk * 32);
            const float4* hv  = reinterpret_cast<const float4*>(sm + HSB + hk * 32);
            float acc = 0.0f;
#pragma unroll
            for (int k = 0; k < 8; ++k) { float4 wv = whh[k], xv = hv[k]; FMA4(acc, wv, xv) }
            acc += __shfl_xor(acc, 1);
            if (hk == 0) {
                const float4* wih = reinterpret_cast<const float4*>(eWih + j * 8);
                float4 a0 = wih[0], a1 = wih[1];
                float acc2 = ebih[j] + ebhh[j];
                acc2 = fmaf(a0.x, win[0], acc2); acc2 = fmaf(a0.y, win[1], acc2);
                acc2 = fmaf(a0.z, win[2], acc2); acc2 = fmaf(a0.w, win[3], acc2);
                acc2 = fmaf(a1.x, win[4], acc2); acc2 = fmaf(a1.y, win[5], acc2);
                acc2 = fmaf(a1.z, win[6], acc2); acc2 = fmaf(a1.w, win[7], acc2);
                sm[GBUF + j] = acc + acc2;
            }
        }
        __syncthreads(); // D
        // (h) gates -> h,s ; encoded row
        if (tid < 64) {
            float gi = sm[GBUF + tid],       gf = sm[GBUF + 64 + tid];
            float gg = sm[GBUF + 128 + tid], go = sm[GBUF + 192 + tid];
            float c = fsigm(gf) * sm[HSB + 64 + tid] + fsigm(gi) * ftanh(gg);
            float h = fsigm(go) * ftanh(c);
            sm[HSB + tid] = h;
            sm[HSB + 64 + tid] = c;
            sm[ENC + t * 64 + tid] = h;
        }
        __syncthreads(); // E
    }

    // ===== decoder const staging + Uenc post-pass =====
    if (tid < 64)  sm[DC_VD + tid] = vdw[tid];
    if (tid < 65)  sm[DC_WT + tid] = wtw[tid];
    if (tid < 256) { sm[DC_DWIH + tid] = dWih[tid]; sm[DC_DBIAS + tid] = dbih[tid] + dbhh[tid]; }
    if (tid < 64)  { sm[DC_WDB + tid] = Wdb[tid]; sm[DC_WYB + tid] = Wyb[tid]; sm[DC_VY + tid] = vyw[tid]; }
    if (tid < 64)  sm[XVE + tid * 2 + 1] = vdw[tid];
    if (tid < 128) { sm[HSB + tid] = 0.0f; sm[DC_YH + tid] = yh[(size_t)b * TSTEPS + tid]; }
    if (tid == 0)  { sm[DC_SC] = wtb[0]; sm[DC_SC + 1] = vyb[0]; }
    // Uenc[j][tt] = sum_k Ud[j][k] * ENC[tt][k]  (transposed, stride 136)
    {
        int j = tid >> 3, e8 = tid & 7;
        float acc[16];
#pragma unroll
        for (int i = 0; i < 16; ++i) acc[i] = 0.0f;
#pragma unroll
        for (int kc = 0; kc < 4; ++kc) {
            const float4* ud = reinterpret_cast<const float4*>(Udw + j * 64 + kc * 16);
            float4 u0 = ud[0], u1 = ud[1], u2 = ud[2], u3 = ud[3];
#pragma unroll
            for (int i = 0; i < 16; ++i) {
                const float4* er = reinterpret_cast<const float4*>(sm + ENC + (e8 * 16 + i) * 64 + kc * 16);
                float4 e0 = er[0], e1 = er[1], e2 = er[2], e3 = er[3];
                float a = acc[i];
                FMA4(a, u0, e0) FMA4(a, u1, e1) FMA4(a, u2, e2) FMA4(a, u3, e3)
                acc[i] = a;
            }
        }
#pragma unroll
        for (int i4 = 0; i4 < 4; ++i4) {
            *reinterpret_cast<float4*>(sm + UENC + j * 136 + e8 * 16 + i4 * 4) =
                make_float4(acc[i4 * 4], acc[i4 * 4 + 1], acc[i4 * 4 + 2], acc[i4 * 4 + 3]);
        }
    }
    __syncthreads();

    // ===================== DECODER =====================
    for (int t = 0; t < TSTEPS; ++t) {
        // (a) x1[j] = [d,sp].Wd_w[j,:] + Wd_b[j]
        {
            int j = tid >> 3, o = tid & 7;
            const float4* wd = reinterpret_cast<const float4*>(Wdw + j * 128 + o * 16);
            const float4* dv = reinterpret_cast<const float4*>(sm + HSB + o * 16);
            float acc = 0.0f;
#pragma unroll
            for (int k = 0; k < 4; ++k) { float4 wv = wd[k], xv = dv[k]; FMA4(acc, wv, xv) }
            acc += __shfl_xor(acc, 1);
            acc += __shfl_xor(acc, 2);
            acc += __shfl_xor(acc, 4);
            if (o == 0) sm[XVE + j * 2] = acc + sm[DC_WDB + j];
        }
        __syncthreads(); // A
        // (b) l[tt] = sum_j tanh(x1[j] + Uenc[j][tt]) * vd[j]
        {
            int tt = tid >> 2, q = tid & 3;
            float acc = 0.0f;
#pragma unroll
            for (int jj = 0; jj < 16; ++jj) {
                int j = jj * 4 + q;
                float u = sm[UENC + j * 136 + tt];
                float2 xv = *reinterpret_cast<const float2*>(sm + XVE + j * 2);
                acc = fmaf(ftanh(xv.x + u), xv.y, acc);
            }
            acc += __shfl_xor(acc, 1);
            acc += __shfl_xor(acc, 2);
            if (q == 0) sm[LBUF + tt] = acc;
        }
        __syncthreads(); // B
        // (c) softmax over 128 tt (wave 0)
        if (tid < 64) {
            float v0 = sm[LBUF + tid], v1 = sm[LBUF + 64 + tid];
            float mx = fmaxf(v0, v1);
#pragma unroll
            for (int dd = 1; dd < 64; dd <<= 1) mx = fmaxf(mx, __shfl_xor(mx, dd));
            float e0 = __expf(v0 - mx), e1 = __expf(v1 - mx);
            float s = e0 + e1;
#pragma unroll
            for (int dd = 1; dd < 64; dd <<= 1) s += __shfl_xor(s, dd);
            float r = rcpf(s);
            sm[LBUF + tid] = e0 * r;
            sm[LBUF + 64 + tid] = e1 * r;
        }
        __syncthreads(); // C
        // hhdot prefetch (global latency overlaps (d)) + (d) c_t partials
        float hacc = 0.0f;
        {
            int j = tid >> 1, hk = tid & 1;
            const float4* whh = reinterpret_cast<const float4*>(dWhh + j * 64 + hk * 32);
            const float4* dv  = reinterpret_cast<const float4*>(sm + HSB + hk * 32);
#pragma unroll
            for (int k = 0; k < 8; ++k) { float4 wv = whh[k], xv = dv[k]; FMA4(hacc, wv, xv) }
        }
        {
            int j = tid & 63, cc = tid >> 6;
            float acc = 0.0f;
#pragma unroll
            for (int i = 0; i < 16; ++i) {
                int ttk = cc * 16 + i;
                acc = fmaf(sm[LBUF + ttk], sm[ENC + ttk * 64 + j], acc);
            }
            sm[GBUF + cc * 64 + j] = acc;
        }
        __syncthreads(); // D
        // (e) finish c_t + y_tilda (wave 0)
        if (tid < 64) {
            float cv = 0.0f;
#pragma unroll
            for (int cc = 0; cc < 8; ++cc) cv += sm[GBUF + cc * 64 + tid];
            sm[CTV + tid] = cv;
            float p = cv * sm[DC_WT + tid];
#pragma unroll
            for (int dd = 1; dd < 64; dd <<= 1) p += __shfl_xor(p, dd);
            if (tid == 0)
                sm[REDS] = p + sm[DC_YH + t] * sm[DC_WT + 64] + sm[DC_SC];
        }
        __syncthreads(); // E
        // (f2) preact = hh + y*Wih + bias
        {
            int j = tid >> 1, hk = tid & 1;
            float acc = hacc + __shfl_xor(hacc, 1);
            if (hk == 0) {
                float yt = sm[REDS];
                sm[GB2 + j] = acc + fmaf(yt, sm[DC_DWIH + j], sm[DC_DBIAS + j]);
            }
        }
        __syncthreads(); // F
        // (g) gates -> d, sp
        if (tid < 64) {
            float gi = sm[GB2 + tid],       gf = sm[GB2 + 64 + tid];
            float gg = sm[GB2 + 128 + tid], go = sm[GB2 + 192 + tid];
            float c = fsigm(gf) * sm[HSB + 64 + tid] + fsigm(gi) * ftanh(gg);
            float dnew = fsigm(go) * ftanh(c);
            sm[HSB + tid] = dnew;
            sm[HSB + 64 + tid] = c;
        }
        __syncthreads(); // G
    }

    // ===================== HEAD =====================
    {
        int p = tid >> 3, o = tid & 7;
        const float4* wy = reinterpret_cast<const float4*>(Wyw + p * 128 + o * 16);
        const float4* sv = reinterpret_cast<const float4*>(
            (o < 4) ? (sm + HSB + o * 16) : (sm + CTV + (o - 4) * 16));
        float acc = 0.0f;
#pragma unroll
        for (int k = 0; k < 4; ++k) { float4 wv = wy[k], xv = sv[k]; FMA4(acc, wv, xv) }
        acc += __shfl_xor(acc, 1);
        acc += __shfl_xor(acc, 2);
        acc += __shfl_xor(acc, 4);
        if (o == 0) sm[TYP + p] = acc + sm[DC_WYB + p];
    }
    __syncthreads();
    if (tid < 64) {
        float v = sm[TYP + tid] * sm[DC_VY + tid];
#pragma unroll
        for (int dd = 1; dd < 64; dd <<= 1) v += __shfl_xor(v, dd);
        if (tid == 0) out[b] = v + sm[DC_SC + 1];
    }
}

extern "C" void kernel_launch(void* const* d_in, const int* in_sizes, int n_in,
                              void* d_out, int out_size, void* d_ws, size_t ws_size,
                              hipStream_t stream) {
    const float* A[26];
    for (int i = 0; i < 26; ++i) A[i] = (const float*)d_in[i];
    (void)in_sizes; (void)n_in; (void)d_ws; (void)ws_size; (void)out_size;

    (void)hipFuncSetAttribute(reinterpret_cast<const void*>(dstp_kernel),
                              hipFuncAttributeMaxDynamicSharedMemorySize,
                              SMEMF * 4);

    dstp_kernel<<<dim3(512), dim3(512), SMEMF * 4, stream>>>(
        A[0], A[1], A[2], A[3], A[4], A[5], A[6], A[7], A[8], A[9],
        A[10], A[11], A[12], A[13], A[14], A[15], A[16], A[17], A[18], A[19],
        A[20], A[21], A[22], A[23], A[24], A[25], (float*)d_out);
}

// Round 5
// 1712.987 us; speedup vs baseline: 1.9602x; 1.9602x over previous
//
#include <hip/hip_runtime.h>

// DSTP-RNN fused forward v3: one batch element per 512-thread WG (8 waves).
// Fixes vs v2: (1) __launch_bounds__(512,2) -> 128-VGPR cap (v2's (512,4) was
// interpreted as 4 blocks/CU -> 64 VGPR -> scratch spill -> 3.4GB HBM traffic);
// (2) conflict-free LDS layouts: CTLT [8][72], HSB chunked stride-36, UENC stride-137.

#define TSTEPS 128

// LDS float offsets
#define ENC    0        // [128][64] encoded h (lane-major)
#define UENC   8192     // [64][137] Uenc transposed (137%32=9 -> 2-way reads/writes)
#define UE     16960    // 1024: Ue_w (encoder) ; decoder const pool overlays
#define CTLT   17984    // [8][72] conv tile transposed ; DC_YH overlays (decoder)
#define XVE    18560    // [128][2] interleaved (x_j, ve_j) / (x1_j, vd_j)
#define HSB4   18816    // 144: [h|s] (or [d|sp]) as 4 chunks of 32 @ stride 36
#define GBUF   18960    // [512] partials
#define RED    19472    // [512] enc e-partials ; GB2 (dec preacts) overlays
#define REDS   19984    // [8] scalars
#define IMG    19992    // [84] 9x9 image ; TYP (head) overlays
#define CTV    20076    // [64] decoder c_t
#define LBUF   20140    // [128] l / beta
#define SMEMF  20268    // floats -> 81072 B -> 2 WG/CU (162144 of 163840)

// decoder const overlays (UE region)
#define DC_VD    (UE + 0)
#define DC_WT    (UE + 64)    // 65
#define DC_DWIH  (UE + 192)   // 256
#define DC_DBIAS (UE + 448)   // 256
#define DC_WDB   (UE + 704)   // 64
#define DC_WYB   (UE + 768)   // 64
#define DC_VY    (UE + 832)   // 64
#define DC_SC    (UE + 896)   // wtb, vyb
#define DC_YH    CTLT         // 128
#define GB2      RED
#define TYP      IMG

// state-vector chunk addressing: element i of 128-vector -> chunk i>>5 @ stride 36
#define HS(i) (HSB4 + ((i) >> 5) * 36 + ((i) & 31))

__device__ __forceinline__ float rcpf(float x) { return __builtin_amdgcn_rcpf(x); }
__device__ __forceinline__ float fsigm(float x) { return rcpf(1.0f + __expf(-x)); }
__device__ __forceinline__ float ftanh(float x) { return 1.0f - 2.0f * rcpf(1.0f + __expf(2.0f * x)); }

#define FMA4(d_, p_, q_) \
    d_ = fmaf((p_).x, (q_).x, d_); d_ = fmaf((p_).y, (q_).y, d_); \
    d_ = fmaf((p_).z, (q_).z, d_); d_ = fmaf((p_).w, (q_).w, d_);

__global__ __launch_bounds__(512, 2) void dstp_kernel(
    const float* __restrict__ Xh,   const float* __restrict__ yh,
    const float* __restrict__ convw,const float* __restrict__ convb,
    const float* __restrict__ Wew,  const float* __restrict__ Web,
    const float* __restrict__ Uew,  const float* __restrict__ vew,
    const float* __restrict__ eWih, const float* __restrict__ eWhh,
    const float* __restrict__ ebih, const float* __restrict__ ebhh,
    const float* __restrict__ Wdw,  const float* __restrict__ Wdb,
    const float* __restrict__ Udw,  const float* __restrict__ vdw,
    const float* __restrict__ wtw,  const float* __restrict__ wtb,
    const float* __restrict__ dWih, const float* __restrict__ dWhh,
    const float* __restrict__ dbih, const float* __restrict__ dbhh,
    const float* __restrict__ Wyw,  const float* __restrict__ Wyb,
    const float* __restrict__ vyw,  const float* __restrict__ vyb,
    float* __restrict__ out)
{
    extern __shared__ float sm[];
    const int tid = threadIdx.x;
    const int b   = blockIdx.x;

    // init: stage Ue_w, ve into XVE.y, zero state chunks
    for (int i = tid; i < 1024; i += 512) sm[UE + i] = Uew[i];
    if (tid < 128) sm[XVE + tid * 2 + 1] = vew[tid];
    if (tid < 144) sm[HSB4 + tid] = 0.0f;
    __syncthreads();

    // ===================== ENCODER =====================
    for (int t = 0; t < TSTEPS; ++t) {
        // img load + (c) x[j] = [h,s].We_w[j,:] + We_b[j]  (j=tid>>2, q=chunk)
        if (tid < 81) sm[IMG + tid] = Xh[((size_t)b * TSTEPS + t) * 81 + tid];
        {
            int j = tid >> 2, q = tid & 3;
            const float4* wr = reinterpret_cast<const float4*>(Wew + j * 128 + q * 32);
            const float4* hv = reinterpret_cast<const float4*>(sm + HSB4 + q * 36);
            float acc = 0.0f;
#pragma unroll
            for (int k = 0; k < 8; ++k) { float4 wv = wr[k], xv = hv[k]; FMA4(acc, wv, xv) }
            acc += __shfl_xor(acc, 1);
            acc += __shfl_xor(acc, 2);
            if (q == 0) sm[XVE + j * 2] = acc + Web[j];
        }
        __syncthreads(); // A
        // conv + relu -> CTLT[r][m]
        {
            int m = tid >> 3, r = tid & 7;
            const float* kw = convw + m * 18;
            float acc = convb[m];
#pragma unroll
            for (int w = 0; w < 9; ++w) {
                acc = fmaf(sm[IMG + r * 9 + w],     kw[w],     acc);
                acc = fmaf(sm[IMG + r * 9 + 9 + w], kw[9 + w], acc);
            }
            sm[CTLT + r * 72 + m] = fmaxf(acc, 0.0f);
        }
        __syncthreads(); // B
        const int m = tid & 63;
        float cr[8];
#pragma unroll
        for (int c = 0; c < 8; ++c) cr[c] = sm[CTLT + c * 72 + m];
        // (d) e partials: lane=m, wave w covers 16 j (Ue rows broadcast)
        {
            int w = tid >> 6;
            float eacc = 0.0f;
#pragma unroll
            for (int jj = 0; jj < 16; ++jj) {
                int j = w * 16 + jj;
                float4 u0 = *reinterpret_cast<const float4*>(sm + UE + j * 8);
                float4 u1 = *reinterpret_cast<const float4*>(sm + UE + j * 8 + 4);
                float2 xv = *reinterpret_cast<const float2*>(sm + XVE + j * 2);
                float s = xv.x;
                s = fmaf(u0.x, cr[0], s); s = fmaf(u0.y, cr[1], s);
                s = fmaf(u0.z, cr[2], s); s = fmaf(u0.w, cr[3], s);
                s = fmaf(u1.x, cr[4], s); s = fmaf(u1.y, cr[5], s);
                s = fmaf(u1.z, cr[6], s); s = fmaf(u1.w, cr[7], s);
                eacc = fmaf(ftanh(s), xv.y, eacc);
            }
            sm[RED + w * 64 + m] = eacc;
        }
        __syncthreads(); // C
        // (ef) per-wave redundant softmax + w_in butterfly (all lanes end with w_in)
        float win[8];
        {
            float e = 0.0f;
#pragma unroll
            for (int p = 0; p < 8; ++p) e += sm[RED + p * 64 + m];
            float mx = e;
#pragma unroll
            for (int dd = 1; dd < 64; dd <<= 1) mx = fmaxf(mx, __shfl_xor(mx, dd));
            float ex = __expf(e - mx);
            float ssum = ex;
#pragma unroll
            for (int dd = 1; dd < 64; dd <<= 1) ssum += __shfl_xor(ssum, dd);
            float al = ex * rcpf(ssum);
#pragma unroll
            for (int c = 0; c < 8; ++c) win[c] = al * cr[c];
#pragma unroll
            for (int dd = 1; dd < 64; dd <<= 1) {
#pragma unroll
                for (int c = 0; c < 8; ++c) win[c] += __shfl_xor(win[c], dd);
            }
        }
        // (g) LSTM preact row j (w_in in regs; h from chunk hk)
        {
            int j = tid >> 1, hk = tid & 1;
            const float4* whh = reinterpret_cast<const float4*>(eWhh + j * 64 + hk * 32);
            const float4* hv  = reinterpret_cast<const float4*>(sm + HSB4 + hk * 36);
            float acc = 0.0f;
#pragma unroll
            for (int k = 0; k < 8; ++k) { float4 wv = whh[k], xv = hv[k]; FMA4(acc, wv, xv) }
            acc += __shfl_xor(acc, 1);
            if (hk == 0) {
                const float4* wih = reinterpret_cast<const float4*>(eWih + j * 8);
                float4 a0 = wih[0], a1 = wih[1];
                float acc2 = ebih[j] + ebhh[j];
                acc2 = fmaf(a0.x, win[0], acc2); acc2 = fmaf(a0.y, win[1], acc2);
                acc2 = fmaf(a0.z, win[2], acc2); acc2 = fmaf(a0.w, win[3], acc2);
                acc2 = fmaf(a1.x, win[4], acc2); acc2 = fmaf(a1.y, win[5], acc2);
                acc2 = fmaf(a1.z, win[6], acc2); acc2 = fmaf(a1.w, win[7], acc2);
                sm[GBUF + j] = acc + acc2;
            }
        }
        __syncthreads(); // D
        // (h) gates -> h,s ; encoded row
        if (tid < 64) {
            float gi = sm[GBUF + tid],       gf = sm[GBUF + 64 + tid];
            float gg = sm[GBUF + 128 + tid], go = sm[GBUF + 192 + tid];
            float c = fsigm(gf) * sm[HS(64 + tid)] + fsigm(gi) * ftanh(gg);
            float h = fsigm(go) * ftanh(c);
            sm[HS(tid)] = h;
            sm[HS(64 + tid)] = c;
            sm[ENC + t * 64 + tid] = h;
        }
        __syncthreads(); // E
    }

    // ===== decoder const staging + Uenc post-pass =====
    if (tid < 64)  sm[DC_VD + tid] = vdw[tid];
    if (tid < 65)  sm[DC_WT + tid] = wtw[tid];
    if (tid < 256) { sm[DC_DWIH + tid] = dWih[tid]; sm[DC_DBIAS + tid] = dbih[tid] + dbhh[tid]; }
    if (tid < 64)  { sm[DC_WDB + tid] = Wdb[tid]; sm[DC_WYB + tid] = Wyb[tid]; sm[DC_VY + tid] = vyw[tid]; }
    if (tid < 64)  sm[XVE + tid * 2 + 1] = vdw[tid];
    if (tid < 144) sm[HSB4 + tid] = 0.0f;            // d, sp = 0
    if (tid < 128) sm[DC_YH + tid] = yh[(size_t)b * TSTEPS + tid];
    if (tid == 0)  { sm[DC_SC] = wtb[0]; sm[DC_SC + 1] = vyb[0]; }
    // Uenc[j][tt] = sum_k Ud[j][k]*ENC[tt][k]; j=lane (write 2-way), ENC reads broadcast
    {
        int j = tid & 63, e8 = tid >> 6;
        float acc[16];
#pragma unroll
        for (int i = 0; i < 16; ++i) acc[i] = 0.0f;
#pragma unroll
        for (int kc = 0; kc < 4; ++kc) {
            const float4* ud = reinterpret_cast<const float4*>(Udw + j * 64 + kc * 16);
            float4 u0 = ud[0], u1 = ud[1], u2 = ud[2], u3 = ud[3];
#pragma unroll
            for (int i = 0; i < 16; ++i) {
                const float4* er = reinterpret_cast<const float4*>(sm + ENC + (e8 * 16 + i) * 64 + kc * 16);
                float4 e0 = er[0], e1 = er[1], e2 = er[2], e3 = er[3];
                float a = acc[i];
                FMA4(a, u0, e0) FMA4(a, u1, e1) FMA4(a, u2, e2) FMA4(a, u3, e3)
                acc[i] = a;
            }
        }
#pragma unroll
        for (int i = 0; i < 16; ++i)
            sm[UENC + j * 137 + e8 * 16 + i] = acc[i];
    }
    __syncthreads();

    // ===================== DECODER =====================
    for (int t = 0; t < TSTEPS; ++t) {
        // (a) x1[j] = [d,sp].Wd_w[j,:] + Wd_b[j]  (o = 16-float piece, chunked)
        {
            int j = tid >> 3, o = tid & 7;
            const float4* wd = reinterpret_cast<const float4*>(Wdw + j * 128 + o * 16);
            const float4* dv = reinterpret_cast<const float4*>(sm + HSB4 + (o >> 1) * 36 + (o & 1) * 16);
            float acc = 0.0f;
#pragma unroll
            for (int k = 0; k < 4; ++k) { float4 wv = wd[k], xv = dv[k]; FMA4(acc, wv, xv) }
            acc += __shfl_xor(acc, 1);
            acc += __shfl_xor(acc, 2);
            acc += __shfl_xor(acc, 4);
            if (o == 0) sm[XVE + j * 2] = acc + sm[DC_WDB + j];
        }
        __syncthreads(); // A
        // (b) l[tt] = sum_j tanh(x1[j] + Uenc[j][tt]) * vd[j]
        {
            int tt = tid >> 2, q = tid & 3;
            float acc = 0.0f;
#pragma unroll
            for (int jj = 0; jj < 16; ++jj) {
                int j = jj * 4 + q;
                float u = sm[UENC + j * 137 + tt];
                float2 xv = *reinterpret_cast<const float2*>(sm + XVE + j * 2);
                acc = fmaf(ftanh(xv.x + u), xv.y, acc);
            }
            acc += __shfl_xor(acc, 1);
            acc += __shfl_xor(acc, 2);
            if (q == 0) sm[LBUF + tt] = acc;
        }
        __syncthreads(); // B
        // (c) softmax over 128 tt (wave 0)
        if (tid < 64) {
            float v0 = sm[LBUF + tid], v1 = sm[LBUF + 64 + tid];
            float mx = fmaxf(v0, v1);
#pragma unroll
            for (int dd = 1; dd < 64; dd <<= 1) mx = fmaxf(mx, __shfl_xor(mx, dd));
            float e0 = __expf(v0 - mx), e1 = __expf(v1 - mx);
            float s = e0 + e1;
#pragma unroll
            for (int dd = 1; dd < 64; dd <<= 1) s += __shfl_xor(s, dd);
            float r = rcpf(s);
            sm[LBUF + tid] = e0 * r;
            sm[LBUF + 64 + tid] = e1 * r;
        }
        __syncthreads(); // C
        // hhdot (global-latency overlap) + (d) c_t partials
        float hacc = 0.0f;
        {
            int j = tid >> 1, hk = tid & 1;
            const float4* whh = reinterpret_cast<const float4*>(dWhh + j * 64 + hk * 32);
            const float4* dv  = reinterpret_cast<const float4*>(sm + HSB4 + hk * 36);
#pragma unroll
            for (int k = 0; k < 8; ++k) { float4 wv = whh[k], xv = dv[k]; FMA4(hacc, wv, xv) }
        }
        {
            int j = tid & 63, cc = tid >> 6;
            float acc = 0.0f;
#pragma unroll
            for (int i = 0; i < 16; ++i) {
                int ttk = cc * 16 + i;
                acc = fmaf(sm[LBUF + ttk], sm[ENC + ttk * 64 + j], acc);
            }
            sm[GBUF + cc * 64 + j] = acc;
        }
        __syncthreads(); // D
        // (e) finish c_t + y_tilda (wave 0)
        if (tid < 64) {
            float cv = 0.0f;
#pragma unroll
            for (int cc = 0; cc < 8; ++cc) cv += sm[GBUF + cc * 64 + tid];
            sm[CTV + tid] = cv;
            float p = cv * sm[DC_WT + tid];
#pragma unroll
            for (int dd = 1; dd < 64; dd <<= 1) p += __shfl_xor(p, dd);
            if (tid == 0)
                sm[REDS] = p + sm[DC_YH + t] * sm[DC_WT + 64] + sm[DC_SC];
        }
        __syncthreads(); // E
        // (f2) preact = hh + y*Wih + bias
        {
            int j = tid >> 1, hk = tid & 1;
            float acc = hacc + __shfl_xor(hacc, 1);
            if (hk == 0) {
                float yt = sm[REDS];
                sm[GB2 + j] = acc + fmaf(yt, sm[DC_DWIH + j], sm[DC_DBIAS + j]);
            }
        }
        __syncthreads(); // F
        // (g) gates -> d, sp
        if (tid < 64) {
            float gi = sm[GB2 + tid],       gf = sm[GB2 + 64 + tid];
            float gg = sm[GB2 + 128 + tid], go = sm[GB2 + 192 + tid];
            float c = fsigm(gf) * sm[HS(64 + tid)] + fsigm(gi) * ftanh(gg);
            float dnew = fsigm(go) * ftanh(c);
            sm[HS(tid)] = dnew;
            sm[HS(64 + tid)] = c;
        }
        __syncthreads(); // G
    }

    // ===================== HEAD =====================
    {
        int p = tid >> 3, o = tid & 7;
        const float4* wy = reinterpret_cast<const float4*>(Wyw + p * 128 + o * 16);
        const float4* sv = reinterpret_cast<const float4*>(
            (o < 4) ? (sm + HSB4 + (o >> 1) * 36 + (o & 1) * 16)
                    : (sm + CTV + (o - 4) * 16));
        float acc = 0.0f;
#pragma unroll
        for (int k = 0; k < 4; ++k) { float4 wv = wy[k], xv = sv[k]; FMA4(acc, wv, xv) }
        acc += __shfl_xor(acc, 1);
        acc += __shfl_xor(acc, 2);
        acc += __shfl_xor(acc, 4);
        if (o == 0) sm[TYP + p] = acc + sm[DC_WYB + p];
    }
    __syncthreads();
    if (tid < 64) {
        float v = sm[TYP + tid] * sm[DC_VY + tid];
#pragma unroll
        for (int dd = 1; dd < 64; dd <<= 1) v += __shfl_xor(v, dd);
        if (tid == 0) out[b] = v + sm[DC_SC + 1];
    }
}

extern "C" void kernel_launch(void* const* d_in, const int* in_sizes, int n_in,
                              void* d_out, int out_size, void* d_ws, size_t ws_size,
                              hipStream_t stream) {
    const float* A[26];
    for (int i = 0; i < 26; ++i) A[i] = (const float*)d_in[i];
    (void)in_sizes; (void)n_in; (void)d_ws; (void)ws_size; (void)out_size;

    (void)hipFuncSetAttribute(reinterpret_cast<const void*>(dstp_kernel),
                              hipFuncAttributeMaxDynamicSharedMemorySize,
                              SMEMF * 4);

    dstp_kernel<<<dim3(512), dim3(512), SMEMF * 4, stream>>>(
        A[0], A[1], A[2], A[3], A[4], A[5], A[6], A[7], A[8], A[9],
        A[10], A[11], A[12], A[13], A[14], A[15], A[16], A[17], A[18], A[19],
        A[20], A[21], A[22], A[23], A[24], A[25], (float*)d_out);
}

// Round 6
// 1705.166 us; speedup vs baseline: 1.9692x; 1.0046x over previous
//
#include <hip/hip_runtime.h>

// DSTP-RNN fused forward v4: one batch element per 512-thread WG (8 waves).
// v3 fixed the VGPR spill (124 regs); v4 trims LDS 81072 -> 80400 B so TWO
// WGs fit per CU again (round-4 evidence: 80496 B -> 47% occupancy).
// Trims: UENC stride 137->136, CTLT 72->68, REDS overlays LBUF, CTV overlays RED+256.

#define TSTEPS 128

// LDS float offsets (total 20100 floats = 80400 B; 2 WG/CU of 160 KiB)
#define ENC    0        // [128][64] encoded h (lane-major)
#define UENC   8192     // [64][136] Uenc transposed (136%32=8 -> 2-way reads)
#define UE     16896    // 1024: Ue_w (encoder) ; decoder const pool overlays
#define CTLT   17920    // [8][68] conv tile transposed ; DC_YH overlays (decoder)
#define XVE    18464    // [128][2] interleaved (x_j, ve_j) / (x1_j, vd_j)
#define HSB4   18720    // 144: [h|s] (or [d|sp]) as 4 chunks of 32 @ stride 36
#define GBUF   18864    // [512] partials
#define RED    19376    // [512] enc e-partials ; GB2 (dec preacts, 256) + CTV (at +256) overlay
#define IMG    19888    // [84] 9x9 image ; TYP (head) overlays
#define LBUF   19972    // [128] l / beta ; REDS overlays (disjoint intervals)
#define SMEMF  20100    // floats -> 80400 bytes

// decoder const overlays (UE region)
#define DC_VD    (UE + 0)
#define DC_WT    (UE + 64)    // 65
#define DC_DWIH  (UE + 192)   // 256
#define DC_DBIAS (UE + 448)   // 256
#define DC_WDB   (UE + 704)   // 64
#define DC_WYB   (UE + 768)   // 64
#define DC_VY    (UE + 832)   // 64
#define DC_SC    (UE + 896)   // wtb, vyb
#define DC_YH    CTLT         // 128
#define GB2      RED          // 256 (dec preacts)
#define CTV      (RED + 256)  // 64 (dec c_t; survives loop for head)
#define TYP      IMG
#define REDS     LBUF         // scalar y_tilda (D->E write, E->F read; LBUF idle there)

// state-vector chunk addressing: element i of 128-vector -> chunk i>>5 @ stride 36
#define HS(i) (HSB4 + ((i) >> 5) * 36 + ((i) & 31))

__device__ __forceinline__ float rcpf(float x) { return __builtin_amdgcn_rcpf(x); }
__device__ __forceinline__ float fsigm(float x) { return rcpf(1.0f + __expf(-x)); }
__device__ __forceinline__ float ftanh(float x) { return 1.0f - 2.0f * rcpf(1.0f + __expf(2.0f * x)); }

#define FMA4(d_, p_, q_) \
    d_ = fmaf((p_).x, (q_).x, d_); d_ = fmaf((p_).y, (q_).y, d_); \
    d_ = fmaf((p_).z, (q_).z, d_); d_ = fmaf((p_).w, (q_).w, d_);

__global__ __launch_bounds__(512, 2) void dstp_kernel(
    const float* __restrict__ Xh,   const float* __restrict__ yh,
    const float* __restrict__ convw,const float* __restrict__ convb,
    const float* __restrict__ Wew,  const float* __restrict__ Web,
    const float* __restrict__ Uew,  const float* __restrict__ vew,
    const float* __restrict__ eWih, const float* __restrict__ eWhh,
    const float* __restrict__ ebih, const float* __restrict__ ebhh,
    const float* __restrict__ Wdw,  const float* __restrict__ Wdb,
    const float* __restrict__ Udw,  const float* __restrict__ vdw,
    const float* __restrict__ wtw,  const float* __restrict__ wtb,
    const float* __restrict__ dWih, const float* __restrict__ dWhh,
    const float* __restrict__ dbih, const float* __restrict__ dbhh,
    const float* __restrict__ Wyw,  const float* __restrict__ Wyb,
    const float* __restrict__ vyw,  const float* __restrict__ vyb,
    float* __restrict__ out)
{
    extern __shared__ float sm[];
    const int tid = threadIdx.x;
    const int b   = blockIdx.x;

    // init: stage Ue_w, ve into XVE.y, zero state chunks
    for (int i = tid; i < 1024; i += 512) sm[UE + i] = Uew[i];
    if (tid < 128) sm[XVE + tid * 2 + 1] = vew[tid];
    if (tid < 144) sm[HSB4 + tid] = 0.0f;
    __syncthreads();

    // ===================== ENCODER =====================
    for (int t = 0; t < TSTEPS; ++t) {
        // img load + (c) x[j] = [h,s].We_w[j,:] + We_b[j]  (j=tid>>2, q=chunk)
        if (tid < 81) sm[IMG + tid] = Xh[((size_t)b * TSTEPS + t) * 81 + tid];
        {
            int j = tid >> 2, q = tid & 3;
            const float4* wr = reinterpret_cast<const float4*>(Wew + j * 128 + q * 32);
            const float4* hv = reinterpret_cast<const float4*>(sm + HSB4 + q * 36);
            float acc = 0.0f;
#pragma unroll
            for (int k = 0; k < 8; ++k) { float4 wv = wr[k], xv = hv[k]; FMA4(acc, wv, xv) }
            acc += __shfl_xor(acc, 1);
            acc += __shfl_xor(acc, 2);
            if (q == 0) sm[XVE + j * 2] = acc + Web[j];
        }
        __syncthreads(); // A
        // conv + relu -> CTLT[r][m]
        {
            int m = tid >> 3, r = tid & 7;
            const float* kw = convw + m * 18;
            float acc = convb[m];
#pragma unroll
            for (int w = 0; w < 9; ++w) {
                acc = fmaf(sm[IMG + r * 9 + w],     kw[w],     acc);
                acc = fmaf(sm[IMG + r * 9 + 9 + w], kw[9 + w], acc);
            }
            sm[CTLT + r * 68 + m] = fmaxf(acc, 0.0f);
        }
        __syncthreads(); // B
        const int m = tid & 63;
        float cr[8];
#pragma unroll
        for (int c = 0; c < 8; ++c) cr[c] = sm[CTLT + c * 68 + m];
        // (d) e partials: lane=m, wave w covers 16 j (Ue rows broadcast)
        {
            int w = tid >> 6;
            float eacc = 0.0f;
#pragma unroll
            for (int jj = 0; jj < 16; ++jj) {
                int j = w * 16 + jj;
                float4 u0 = *reinterpret_cast<const float4*>(sm + UE + j * 8);
                float4 u1 = *reinterpret_cast<const float4*>(sm + UE + j * 8 + 4);
                float2 xv = *reinterpret_cast<const float2*>(sm + XVE + j * 2);
                float s = xv.x;
                s = fmaf(u0.x, cr[0], s); s = fmaf(u0.y, cr[1], s);
                s = fmaf(u0.z, cr[2], s); s = fmaf(u0.w, cr[3], s);
                s = fmaf(u1.x, cr[4], s); s = fmaf(u1.y, cr[5], s);
                s = fmaf(u1.z, cr[6], s); s = fmaf(u1.w, cr[7], s);
                eacc = fmaf(ftanh(s), xv.y, eacc);
            }
            sm[RED + w * 64 + m] = eacc;
        }
        __syncthreads(); // C
        // (ef) per-wave redundant softmax + w_in butterfly (all lanes end with w_in)
        float win[8];
        {
            float e = 0.0f;
#pragma unroll
            for (int p = 0; p < 8; ++p) e += sm[RED + p * 64 + m];
            float mx = e;
#pragma unroll
            for (int dd = 1; dd < 64; dd <<= 1) mx = fmaxf(mx, __shfl_xor(mx, dd));
            float ex = __expf(e - mx);
            float ssum = ex;
#pragma unroll
            for (int dd = 1; dd < 64; dd <<= 1) ssum += __shfl_xor(ssum, dd);
            float al = ex * rcpf(ssum);
#pragma unroll
            for (int c = 0; c < 8; ++c) win[c] = al * cr[c];
#pragma unroll
            for (int dd = 1; dd < 64; dd <<= 1) {
#pragma unroll
                for (int c = 0; c < 8; ++c) win[c] += __shfl_xor(win[c], dd);
            }
        }
        // (g) LSTM preact row j (w_in in regs; h from chunk hk)
        {
            int j = tid >> 1, hk = tid & 1;
            const float4* whh = reinterpret_cast<const float4*>(eWhh + j * 64 + hk * 32);
            const float4* hv  = reinterpret_cast<const float4*>(sm + HSB4 + hk * 36);
            float acc = 0.0f;
#pragma unroll
            for (int k = 0; k < 8; ++k) { float4 wv = whh[k], xv = hv[k]; FMA4(acc, wv, xv) }
            acc += __shfl_xor(acc, 1);
            if (hk == 0) {
                const float4* wih = reinterpret_cast<const float4*>(eWih + j * 8);
                float4 a0 = wih[0], a1 = wih[1];
                float acc2 = ebih[j] + ebhh[j];
                acc2 = fmaf(a0.x, win[0], acc2); acc2 = fmaf(a0.y, win[1], acc2);
                acc2 = fmaf(a0.z, win[2], acc2); acc2 = fmaf(a0.w, win[3], acc2);
                acc2 = fmaf(a1.x, win[4], acc2); acc2 = fmaf(a1.y, win[5], acc2);
                acc2 = fmaf(a1.z, win[6], acc2); acc2 = fmaf(a1.w, win[7], acc2);
                sm[GBUF + j] = acc + acc2;
            }
        }
        __syncthreads(); // D
        // (h) gates -> h,s ; encoded row
        if (tid < 64) {
            float gi = sm[GBUF + tid],       gf = sm[GBUF + 64 + tid];
            float gg = sm[GBUF + 128 + tid], go = sm[GBUF + 192 + tid];
            float c = fsigm(gf) * sm[HS(64 + tid)] + fsigm(gi) * ftanh(gg);
            float h = fsigm(go) * ftanh(c);
            sm[HS(tid)] = h;
            sm[HS(64 + tid)] = c;
            sm[ENC + t * 64 + tid] = h;
        }
        __syncthreads(); // E
    }

    // ===== decoder const staging + Uenc post-pass =====
    if (tid < 64)  sm[DC_VD + tid] = vdw[tid];
    if (tid < 65)  sm[DC_WT + tid] = wtw[tid];
    if (tid < 256) { sm[DC_DWIH + tid] = dWih[tid]; sm[DC_DBIAS + tid] = dbih[tid] + dbhh[tid]; }
    if (tid < 64)  { sm[DC_WDB + tid] = Wdb[tid]; sm[DC_WYB + tid] = Wyb[tid]; sm[DC_VY + tid] = vyw[tid]; }
    if (tid < 64)  sm[XVE + tid * 2 + 1] = vdw[tid];
    if (tid < 144) sm[HSB4 + tid] = 0.0f;            // d, sp = 0
    if (tid < 128) sm[DC_YH + tid] = yh[(size_t)b * TSTEPS + tid];
    if (tid == 0)  { sm[DC_SC] = wtb[0]; sm[DC_SC + 1] = vyb[0]; }
    // Uenc[j][tt] = sum_k Ud[j][k]*ENC[tt][k]; j=lane, ENC reads broadcast
    {
        int j = tid & 63, e8 = tid >> 6;
        float acc[16];
#pragma unroll
        for (int i = 0; i < 16; ++i) acc[i] = 0.0f;
#pragma unroll
        for (int kc = 0; kc < 4; ++kc) {
            const float4* ud = reinterpret_cast<const float4*>(Udw + j * 64 + kc * 16);
            float4 u0 = ud[0], u1 = ud[1], u2 = ud[2], u3 = ud[3];
#pragma unroll
            for (int i = 0; i < 16; ++i) {
                const float4* er = reinterpret_cast<const float4*>(sm + ENC + (e8 * 16 + i) * 64 + kc * 16);
                float4 e0 = er[0], e1 = er[1], e2 = er[2], e3 = er[3];
                float a = acc[i];
                FMA4(a, u0, e0) FMA4(a, u1, e1) FMA4(a, u2, e2) FMA4(a, u3, e3)
                acc[i] = a;
            }
        }
#pragma unroll
        for (int i = 0; i < 16; ++i)
            sm[UENC + j * 136 + e8 * 16 + i] = acc[i];
    }
    __syncthreads();

    // ===================== DECODER =====================
    for (int t = 0; t < TSTEPS; ++t) {
        // (a) x1[j] = [d,sp].Wd_w[j,:] + Wd_b[j]  (o = 16-float piece, chunked)
        {
            int j = tid >> 3, o = tid & 7;
            const float4* wd = reinterpret_cast<const float4*>(Wdw + j * 128 + o * 16);
            const float4* dv = reinterpret_cast<const float4*>(sm + HSB4 + (o >> 1) * 36 + (o & 1) * 16);
            float acc = 0.0f;
#pragma unroll
            for (int k = 0; k < 4; ++k) { float4 wv = wd[k], xv = dv[k]; FMA4(acc, wv, xv) }
            acc += __shfl_xor(acc, 1);
            acc += __shfl_xor(acc, 2);
            acc += __shfl_xor(acc, 4);
            if (o == 0) sm[XVE + j * 2] = acc + sm[DC_WDB + j];
        }
        __syncthreads(); // A
        // (b) l[tt] = sum_j tanh(x1[j] + Uenc[j][tt]) * vd[j]
        {
            int tt = tid >> 2, q = tid & 3;
            float acc = 0.0f;
#pragma unroll
            for (int jj = 0; jj < 16; ++jj) {
                int j = jj * 4 + q;
                float u = sm[UENC + j * 136 + tt];
                float2 xv = *reinterpret_cast<const float2*>(sm + XVE + j * 2);
                acc = fmaf(ftanh(xv.x + u), xv.y, acc);
            }
            acc += __shfl_xor(acc, 1);
            acc += __shfl_xor(acc, 2);
            if (q == 0) sm[LBUF + tt] = acc;
        }
        __syncthreads(); // B
        // (c) softmax over 128 tt (wave 0)
        if (tid < 64) {
            float v0 = sm[LBUF + tid], v1 = sm[LBUF + 64 + tid];
            float mx = fmaxf(v0, v1);
#pragma unroll
            for (int dd = 1; dd < 64; dd <<= 1) mx = fmaxf(mx, __shfl_xor(mx, dd));
            float e0 = __expf(v0 - mx), e1 = __expf(v1 - mx);
            float s = e0 + e1;
#pragma unroll
            for (int dd = 1; dd < 64; dd <<= 1) s += __shfl_xor(s, dd);
            float r = rcpf(s);
            sm[LBUF + tid] = e0 * r;
            sm[LBUF + 64 + tid] = e1 * r;
        }
        __syncthreads(); // C
        // hhdot (LDS/L2-latency overlap) + (d) c_t partials
        float hacc = 0.0f;
        {
            int j = tid >> 1, hk = tid & 1;
            const float4* whh = reinterpret_cast<const float4*>(dWhh + j * 64 + hk * 32);
            const float4* dv  = reinterpret_cast<const float4*>(sm + HSB4 + hk * 36);
#pragma unroll
            for (int k = 0; k < 8; ++k) { float4 wv = whh[k], xv = dv[k]; FMA4(hacc, wv, xv) }
        }
        {
            int j = tid & 63, cc = tid >> 6;
            float acc = 0.0f;
#pragma unroll
            for (int i = 0; i < 16; ++i) {
                int ttk = cc * 16 + i;
                acc = fmaf(sm[LBUF + ttk], sm[ENC + ttk * 64 + j], acc);
            }
            sm[GBUF + cc * 64 + j] = acc;
        }
        __syncthreads(); // D
        // (e) finish c_t + y_tilda (wave 0)
        if (tid < 64) {
            float cv = 0.0f;
#pragma unroll
            for (int cc = 0; cc < 8; ++cc) cv += sm[GBUF + cc * 64 + tid];
            sm[CTV + tid] = cv;
            float p = cv * sm[DC_WT + tid];
#pragma unroll
            for (int dd = 1; dd < 64; dd <<= 1) p += __shfl_xor(p, dd);
            if (tid == 0)
                sm[REDS] = p + sm[DC_YH + t] * sm[DC_WT + 64] + sm[DC_SC];
        }
        __syncthreads(); // E
        // (f2) preact = hh + y*Wih + bias
        {
            int j = tid >> 1, hk = tid & 1;
            float acc = hacc + __shfl_xor(hacc, 1);
            if (hk == 0) {
                float yt = sm[REDS];
                sm[GB2 + j] = acc + fmaf(yt, sm[DC_DWIH + j], sm[DC_DBIAS + j]);
            }
        }
        __syncthreads(); // F
        // (g) gates -> d, sp
        if (tid < 64) {
            float gi = sm[GB2 + tid],       gf = sm[GB2 + 64 + tid];
            float gg = sm[GB2 + 128 + tid], go = sm[GB2 + 192 + tid];
            float c = fsigm(gf) * sm[HS(64 + tid)] + fsigm(gi) * ftanh(gg);
            float dnew = fsigm(go) * ftanh(c);
            sm[HS(tid)] = dnew;
            sm[HS(64 + tid)] = c;
        }
        __syncthreads(); // G
    }

    // ===================== HEAD =====================
    {
        int p = tid >> 3, o = tid & 7;
        const float4* wy = reinterpret_cast<const float4*>(Wyw + p * 128 + o * 16);
        const float4* sv = reinterpret_cast<const float4*>(
            (o < 4) ? (sm + HSB4 + (o >> 1) * 36 + (o & 1) * 16)
                    : (sm + CTV + (o - 4) * 16));
        float acc = 0.0f;
#pragma unroll
        for (int k = 0; k < 4; ++k) { float4 wv = wy[k], xv = sv[k]; FMA4(acc, wv, xv) }
        acc += __shfl_xor(acc, 1);
        acc += __shfl_xor(acc, 2);
        acc += __shfl_xor(acc, 4);
        if (o == 0) sm[TYP + p] = acc + sm[DC_WYB + p];
    }
    __syncthreads();
    if (tid < 64) {
        float v = sm[TYP + tid] * sm[DC_VY + tid];
#pragma unroll
        for (int dd = 1; dd < 64; dd <<= 1) v += __shfl_xor(v, dd);
        if (tid == 0) out[b] = v + sm[DC_SC + 1];
    }
}

extern "C" void kernel_launch(void* const* d_in, const int* in_sizes, int n_in,
                              void* d_out, int out_size, void* d_ws, size_t ws_size,
                              hipStream_t stream) {
    const float* A[26];
    for (int i = 0; i < 26; ++i) A[i] = (const float*)d_in[i];
    (void)in_sizes; (void)n_in; (void)d_ws; (void)ws_size; (void)out_size;

    (void)hipFuncSetAttribute(reinterpret_cast<const void*>(dstp_kernel),
                              hipFuncAttributeMaxDynamicSharedMemorySize,
                              SMEMF * 4);

    dstp_kernel<<<dim3(512), dim3(512), SMEMF * 4, stream>>>(
        A[0], A[1], A[2], A[3], A[4], A[5], A[6], A[7], A[8], A[9],
        A[10], A[11], A[12], A[13], A[14], A[15], A[16], A[17], A[18], A[19],
        A[20], A[21], A[22], A[23], A[24], A[25], (float*)d_out);
}